// Round 8
// baseline (89.803 us; speedup 1.0000x reference)
//
#include <hip/hip_runtime.h>
#include <stdint.h>

#define BATCH 16384
#define NF 768
#define FT 1024
#define RB 32               // batch rows per block
#define GR (2 * RB)         // GEMM rows per block (stm 0-31, nstm 32-63)
#define THREADS 1024
#define NW 16
#define ALD 784             // A-LDS row stride bytes (768 + 16 pad)
#define NKS 12              // 768 / 64 K-steps

typedef int i32x4 __attribute__((ext_vector_type(4)));

// ---- prep: W_ft [FT][NF] f32 -> Wq [FT][NF] i8 (per-row scale 127/absmax) --
__global__ __launch_bounds__(192) void prep_wq(const float* __restrict__ W_ft,
                                               char* __restrict__ Wq,
                                               float* __restrict__ invs) {
    const int o = blockIdx.x;
    const int t = threadIdx.x;
    __shared__ float smax[3];
    __shared__ float sscale;
    const float4 v = *(const float4*)(W_ft + (size_t)o * NF + t * 4);
    float m = fmaxf(fmaxf(fabsf(v.x), fabsf(v.y)), fmaxf(fabsf(v.z), fabsf(v.w)));
    #pragma unroll
    for (int s = 32; s > 0; s >>= 1) m = fmaxf(m, __shfl_down(m, s, 64));
    if ((t & 63) == 0) smax[t >> 6] = m;
    __syncthreads();
    if (t == 0) {
        const float am = fmaxf(fmaxf(smax[0], smax[1]), smax[2]);
        sscale = 127.0f / am;
        invs[o] = am / 127.0f;
    }
    __syncthreads();
    const float s = sscale;
    const float arr[4] = {v.x, v.y, v.z, v.w};
    uint32_t pk = 0;
    #pragma unroll
    for (int j = 0; j < 4; ++j) {
        const int q = (int)rintf(arr[j] * s);
        pk |= ((uint32_t)(unsigned char)(char)q) << (8 * j);
    }
    *(uint32_t*)(Wq + (size_t)o * NF + t * 4) = pk;
}

__device__ __forceinline__ uint32_t pack01(float4 v) {
    return (uint32_t)(v.x != 0.0f) | ((uint32_t)(v.y != 0.0f) << 8)
         | ((uint32_t)(v.z != 0.0f) << 16) | ((uint32_t)(v.w != 0.0f) << 24);
}

// ---- streaming convert: board f32 -> i8 {0,1}. 64 B in -> 16 B out/iter ----
__global__ __launch_bounds__(256) void conv_boards(const float* __restrict__ src,
                                                   unsigned char* __restrict__ dst,
                                                   int n16) {
    for (int i = blockIdx.x * 256 + threadIdx.x; i < n16; i += gridDim.x * 256) {
        const float4* s = (const float4*)src + (size_t)i * 4;
        const float4 a = s[0], b = s[1], c = s[2], d = s[3];
        uint4 o;
        o.x = pack01(a); o.y = pack01(b); o.z = pack01(c); o.w = pack01(d);
        *(uint4*)(dst + (size_t)i * 16) = o;
    }
}

// ---- fused dense i8-MFMA FT + SCReLU + output layer + sigmoid --------------
// PRE8: A staged from pre-converted i8 boards (3 x dwordx4/thread, batched);
// else from f32 boards (r7 path). 16 waves, wave w owns cols [64w,64w+64).
template <bool PRE8>
__global__ __launch_bounds__(THREADS, 4) void nnue_mfma(
    const float* __restrict__ bstm, const float* __restrict__ bnstm,
    const unsigned char* __restrict__ a8s, const unsigned char* __restrict__ a8n,
    const char* __restrict__ Wq, const float* __restrict__ invs,
    const float* __restrict__ b_ft, const float* __restrict__ W_out,
    const float* __restrict__ b_out, float* __restrict__ out)
{
    __shared__ __align__(16) char Albs[GR * ALD];   // 50176 B
    __shared__ float red[GR][NW];                   // 4096 B

    const int t = threadIdx.x;
    const int w = t >> 6;
    const int l = t & 63;
    const int b0 = blockIdx.x * RB;

    if (PRE8) {
        // 64 rows x 48 16B-chunks = 3072; 3 per thread. Batch loads, then write.
        uint4 v[3]; int row[3], c16[3];
        #pragma unroll
        for (int it = 0; it < 3; ++it) {
            const int g = it * THREADS + t;
            row[it] = g / 48; c16[it] = g - row[it] * 48;
            const unsigned char* src = (row[it] < RB)
                ? (a8s + (size_t)(b0 + row[it]) * NF)
                : (a8n + (size_t)(b0 + row[it] - RB) * NF);
            v[it] = *(const uint4*)(src + c16[it] * 16);
        }
        __builtin_amdgcn_sched_barrier(0);   // keep all 3 loads in flight
        #pragma unroll
        for (int it = 0; it < 3; ++it)
            *(uint4*)(&Albs[row[it] * ALD + c16[it] * 16]) = v[it];
    } else {
        float4 sv[12]; int srow[12], sc4[12];
        #pragma unroll
        for (int it = 0; it < 12; ++it) {
            const int g = it * THREADS + t;
            const int row = g / 192;
            const int c4 = g - row * 192;
            const float* src = (row < RB) ? (bstm + (size_t)(b0 + row) * NF)
                                          : (bnstm + (size_t)(b0 + row - RB) * NF);
            sv[it] = *(const float4*)(src + c4 * 4);
            srow[it] = row; sc4[it] = c4;
        }
        __builtin_amdgcn_sched_barrier(0);
        #pragma unroll
        for (int it = 0; it < 12; ++it)
            *(uint32_t*)(&Albs[srow[it] * ALD + sc4[it] * 4]) = pack01(sv[it]);
    }
    __syncthreads();

    // Barrier-free K-loop. A: lane holds A[row=l&15][k]; B: 16 contiguous
    // bytes of Wq[col][.], col = w*64 + c*16 + (l&15).
    const int cl = l & 15;
    const int q = l >> 4;
    const char* bptr = Wq + (size_t)(w * 64 + cl) * NF + q * 16;
    const int aoff = cl * ALD + q * 16;

    i32x4 acc[4][4] = {};
    #pragma unroll 2
    for (int ks = 0; ks < NKS; ++ks) {
        i32x4 bfrag[4];
        #pragma unroll
        for (int c = 0; c < 4; ++c)
            bfrag[c] = *(const i32x4*)(bptr + (size_t)c * 16 * NF + ks * 64);
        i32x4 afrag[4];
        #pragma unroll
        for (int r = 0; r < 4; ++r)
            afrag[r] = *(const i32x4*)(&Albs[aoff + r * 16 * ALD + ks * 64]);
        #pragma unroll
        for (int r = 0; r < 4; ++r)
            #pragma unroll
            for (int c = 0; c < 4; ++c)
                acc[r][c] = __builtin_amdgcn_mfma_i32_16x16x64_i8(
                    afrag[r], bfrag[c], acc[r][c], 0, 0, 0);
    }

    // Epilogue. C/D lane mapping: col=l&15, row=(l>>4)*4+j.
    float ps[4][4] = {};
    #pragma unroll
    for (int c = 0; c < 4; ++c) {
        const int col = w * 64 + c * 16 + cl;
        const float iv = invs[col];
        const float bf = b_ft[col];
        const float wo0 = W_out[col];
        const float wo1 = W_out[FT + col];
        #pragma unroll
        for (int r = 0; r < 4; ++r) {
            const float wo = (r < 2) ? wo0 : wo1;   // rows 0-31 stm, 32-63 nstm
            #pragma unroll
            for (int j = 0; j < 4; ++j) {
                float h = fmaf((float)acc[r][c][j], iv, bf);
                h = fminf(fmaxf(h, 0.0f), 1.0f);
                ps[r][j] = fmaf(h * h, wo, ps[r][j]);
            }
        }
    }
    #pragma unroll
    for (int r = 0; r < 4; ++r)
        #pragma unroll
        for (int j = 0; j < 4; ++j) {
            float v = ps[r][j];
            v += __shfl_xor(v, 1, 64);
            v += __shfl_xor(v, 2, 64);
            v += __shfl_xor(v, 4, 64);
            v += __shfl_xor(v, 8, 64);
            if (cl == 0) red[16 * r + 4 * q + j][w] = v;
        }
    __syncthreads();

    if (t < RB) {
        float x = b_out[0];
        #pragma unroll
        for (int w2 = 0; w2 < NW; ++w2)
            x += red[t][w2] + red[RB + t][w2];
        out[b0 + t] = 1.0f / (1.0f + expf(-x));
    }
}

extern "C" void kernel_launch(void* const* d_in, const int* in_sizes, int n_in,
                              void* d_out, int out_size, void* d_ws, size_t ws_size,
                              hipStream_t stream) {
    const float* board_stm  = (const float*)d_in[0];
    const float* board_nstm = (const float*)d_in[1];
    const float* W_ft       = (const float*)d_in[2];
    const float* b_ft       = (const float*)d_in[3];
    const float* W_out      = (const float*)d_in[4];
    const float* b_out      = (const float*)d_in[5];
    float* out = (float*)d_out;

    char* Wq = (char*)d_ws;                                  // 768 KB
    float* invs = (float*)((char*)d_ws + (size_t)FT * NF);   // 4 KB
    unsigned char* a8s = (unsigned char*)d_ws + (size_t)FT * NF + 4096;
    unsigned char* a8n = a8s + (size_t)BATCH * NF;
    const size_t needed = (size_t)FT * NF + 4096 + 2 * (size_t)BATCH * NF;

    prep_wq<<<FT, 192, 0, stream>>>(W_ft, Wq, invs);
    if (ws_size >= needed) {
        const int n16 = BATCH * NF / 16;   // 786432 chunks per board
        conv_boards<<<1536, 256, 0, stream>>>(board_stm, a8s, n16);
        conv_boards<<<1536, 256, 0, stream>>>(board_nstm, a8n, n16);
        nnue_mfma<true><<<BATCH / RB, THREADS, 0, stream>>>(
            board_stm, board_nstm, a8s, a8n, Wq, invs, b_ft, W_out, b_out, out);
    } else {
        nnue_mfma<false><<<BATCH / RB, THREADS, 0, stream>>>(
            board_stm, board_nstm, a8s, a8n, Wq, invs, b_ft, W_out, b_out, out);
    }
}

// Round 9
// 86.311 us; speedup vs baseline: 1.0405x; 1.0405x over previous
//
#include <hip/hip_runtime.h>
#include <stdint.h>

#define BATCH 16384
#define NF 768
#define FT 1024
#define RB 32               // batch rows per block
#define GR 64               // GEMM rows per block (stm 0-31, nstm 32-63)
#define THREADS 1024
#define NW 16
#define NKS 12              // 768 / 64 K-steps
#define ABLK (NKS * 4 * 64 * 16)   // 49152 B fragment-ordered A per block

typedef int i32x4 __attribute__((ext_vector_type(4)));

// ---- prep: W_ft [FT][NF] f32 -> Wq [FT][NF] i8 (per-row scale 127/absmax) --
__global__ __launch_bounds__(192) void prep_wq(const float* __restrict__ W_ft,
                                               char* __restrict__ Wq,
                                               float* __restrict__ invs) {
    const int o = blockIdx.x;
    const int t = threadIdx.x;
    __shared__ float smax[3];
    __shared__ float sscale;
    const float4 v = *(const float4*)(W_ft + (size_t)o * NF + t * 4);
    float m = fmaxf(fmaxf(fabsf(v.x), fabsf(v.y)), fmaxf(fabsf(v.z), fabsf(v.w)));
    #pragma unroll
    for (int s = 32; s > 0; s >>= 1) m = fmaxf(m, __shfl_down(m, s, 64));
    if ((t & 63) == 0) smax[t >> 6] = m;
    __syncthreads();
    if (t == 0) {
        const float am = fmaxf(fmaxf(smax[0], smax[1]), smax[2]);
        sscale = 127.0f / am;
        invs[o] = am / 127.0f;
    }
    __syncthreads();
    const float s = sscale;
    const float arr[4] = {v.x, v.y, v.z, v.w};
    uint32_t pk = 0;
    #pragma unroll
    for (int j = 0; j < 4; ++j) {
        const int q = (int)rintf(arr[j] * s);
        pk |= ((uint32_t)(unsigned char)(char)q) << (8 * j);
    }
    *(uint32_t*)(Wq + (size_t)o * NF + t * 4) = pk;
}

__device__ __forceinline__ uint32_t pack01(float4 v) {
    return (uint32_t)(v.x != 0.0f) | ((uint32_t)(v.y != 0.0f) << 8)
         | ((uint32_t)(v.z != 0.0f) << 16) | ((uint32_t)(v.w != 0.0f) << 24);
}

// slot within a block's fragment-ordered A for (GEMM row, 16-feature chunk)
__device__ __forceinline__ int frag_slot(int row, int c16) {
    const int r = row >> 4, cl = row & 15;
    const int ks = c16 >> 2, q = c16 & 3;
    return ((ks * 4 + r) << 6) + q * 16 + cl;   // ((ks*4+r)*64 + lane)
}

// ---- conv: boards f32 -> i8 {0,1}, written in MFMA-fragment order ----------
// a8f[block][ks][r][lane][16]; linear coalesced reads, scattered 16B writes.
__global__ __launch_bounds__(256) void conv_boards(const float* __restrict__ bstm,
                                                   const float* __restrict__ bnstm,
                                                   unsigned char* __restrict__ a8f) {
    const int NCH = BATCH * 48;   // 16B chunks per board
    for (int g = blockIdx.x * 256 + threadIdx.x; g < 2 * NCH; g += gridDim.x * 256) {
        const int p = (g >= NCH);
        const int gg = p ? g - NCH : g;
        const int brow = gg / 48;
        const int c16 = gg - brow * 48;
        const float4* src = (const float4*)((p ? bnstm : bstm)
                                            + (size_t)brow * NF + c16 * 16);
        uint4 o;
        o.x = pack01(src[0]); o.y = pack01(src[1]);
        o.z = pack01(src[2]); o.w = pack01(src[3]);
        const int blk = brow >> 5;
        const int row = (p << 5) | (brow & 31);
        *(uint4*)(a8f + (size_t)blk * ABLK + ((size_t)frag_slot(row, c16) << 4)) = o;
    }
}

// ---- fused dense i8-MFMA FT + SCReLU + output layer + sigmoid --------------
// 16 waves, wave w owns cols [64w, 64w+64). A in LDS in fragment order
// (lane-linear reads, zero conflicts). Explicit even/odd B-register pipeline.
template <bool PRE8>
__global__ __launch_bounds__(THREADS, 2) void nnue_mfma(
    const float* __restrict__ bstm, const float* __restrict__ bnstm,
    const unsigned char* __restrict__ a8f,
    const char* __restrict__ Wq, const float* __restrict__ invs,
    const float* __restrict__ b_ft, const float* __restrict__ W_out,
    const float* __restrict__ b_out, float* __restrict__ out)
{
    __shared__ __align__(16) char Albs[ABLK];   // 48 KB
    __shared__ float red[GR][NW];

    const int t = threadIdx.x;
    const int w = t >> 6;
    const int l = t & 63;
    const int b0 = blockIdx.x * RB;

    if (PRE8) {
        // linear copy: 3072 16B chunks, 3 per thread, lane-linear LDS writes
        const uint4* src = (const uint4*)(a8f + (size_t)blockIdx.x * ABLK);
        uint4* dst = (uint4*)Albs;
        const uint4 v0 = src[t], v1 = src[1024 + t], v2 = src[2048 + t];
        dst[t] = v0; dst[1024 + t] = v1; dst[2048 + t] = v2;
    } else {
        // fallback: stage from f32 boards, fragment-order swizzled writes
        #pragma unroll
        for (int it = 0; it < 3; ++it) {
            const int c = it * 1024 + t;
            const int row = c / 48;
            const int c16 = c - row * 48;
            const float4* s = (const float4*)(((row < RB)
                ? (bstm + (size_t)(b0 + row) * NF)
                : (bnstm + (size_t)(b0 + row - RB) * NF)) + c16 * 16);
            uint4 o;
            o.x = pack01(s[0]); o.y = pack01(s[1]);
            o.z = pack01(s[2]); o.w = pack01(s[3]);
            *(uint4*)(Albs + ((size_t)frag_slot(row, c16) << 4)) = o;
        }
    }
    __syncthreads();

    // K-loop: even/odd named B buffers, prefetch one K-step ahead.
    const int cl = l & 15;
    const char* bp = Wq + (size_t)(w * 64 + cl) * NF + (l >> 4) * 16;
    const i32x4* af = (const i32x4*)Albs;   // af[(ks*4+r)*64 + l]

    i32x4 be[4], bo[4];
    #pragma unroll
    for (int c = 0; c < 4; ++c)
        be[c] = *(const i32x4*)(bp + (size_t)c * 16 * NF);

    i32x4 acc[4][4] = {};
    #pragma unroll
    for (int kk = 0; kk < 6; ++kk) {
        const int ks0 = 2 * kk, ks1 = 2 * kk + 1;
        #pragma unroll
        for (int c = 0; c < 4; ++c)
            bo[c] = *(const i32x4*)(bp + (size_t)c * 16 * NF + ks1 * 64);
        __builtin_amdgcn_s_setprio(1);
        #pragma unroll
        for (int r = 0; r < 4; ++r) {
            const i32x4 a = af[(ks0 * 4 + r) * 64 + l];
            #pragma unroll
            for (int c = 0; c < 4; ++c)
                acc[r][c] = __builtin_amdgcn_mfma_i32_16x16x64_i8(
                    a, be[c], acc[r][c], 0, 0, 0);
        }
        __builtin_amdgcn_s_setprio(0);
        if (kk < 5) {
            #pragma unroll
            for (int c = 0; c < 4; ++c)
                be[c] = *(const i32x4*)(bp + (size_t)c * 16 * NF + (ks1 + 1) * 64);
        }
        __builtin_amdgcn_s_setprio(1);
        #pragma unroll
        for (int r = 0; r < 4; ++r) {
            const i32x4 a = af[(ks1 * 4 + r) * 64 + l];
            #pragma unroll
            for (int c = 0; c < 4; ++c)
                acc[r][c] = __builtin_amdgcn_mfma_i32_16x16x64_i8(
                    a, bo[c], acc[r][c], 0, 0, 0);
        }
        __builtin_amdgcn_s_setprio(0);
    }

    // Epilogue. C/D lane mapping: col=l&15, row=(l>>4)*4+j.
    const int q = l >> 4;
    float ps[4][4] = {};
    #pragma unroll
    for (int c = 0; c < 4; ++c) {
        const int col = w * 64 + c * 16 + cl;
        const float iv = invs[col];
        const float bf = b_ft[col];
        const float wo0 = W_out[col];
        const float wo1 = W_out[FT + col];
        #pragma unroll
        for (int r = 0; r < 4; ++r) {
            const float wo = (r < 2) ? wo0 : wo1;   // rows 0-31 stm, 32-63 nstm
            #pragma unroll
            for (int j = 0; j < 4; ++j) {
                float h = fmaf((float)acc[r][c][j], iv, bf);
                h = fminf(fmaxf(h, 0.0f), 1.0f);
                ps[r][j] = fmaf(h * h, wo, ps[r][j]);
            }
        }
    }
    #pragma unroll
    for (int r = 0; r < 4; ++r)
        #pragma unroll
        for (int j = 0; j < 4; ++j) {
            float v = ps[r][j];
            v += __shfl_xor(v, 1, 64);
            v += __shfl_xor(v, 2, 64);
            v += __shfl_xor(v, 4, 64);
            v += __shfl_xor(v, 8, 64);
            if (cl == 0) red[16 * r + 4 * q + j][w] = v;
        }
    __syncthreads();

    if (t < RB) {
        float x = b_out[0];
        #pragma unroll
        for (int w2 = 0; w2 < NW; ++w2)
            x += red[t][w2] + red[RB + t][w2];
        out[b0 + t] = 1.0f / (1.0f + expf(-x));
    }
}

extern "C" void kernel_launch(void* const* d_in, const int* in_sizes, int n_in,
                              void* d_out, int out_size, void* d_ws, size_t ws_size,
                              hipStream_t stream) {
    const float* board_stm  = (const float*)d_in[0];
    const float* board_nstm = (const float*)d_in[1];
    const float* W_ft       = (const float*)d_in[2];
    const float* b_ft       = (const float*)d_in[3];
    const float* W_out      = (const float*)d_in[4];
    const float* b_out      = (const float*)d_in[5];
    float* out = (float*)d_out;

    char* Wq = (char*)d_ws;                                  // 768 KB
    float* invs = (float*)((char*)d_ws + (size_t)FT * NF);   // 4 KB
    unsigned char* a8f = (unsigned char*)d_ws + (size_t)FT * NF + 4096;
    const size_t needed = (size_t)FT * NF + 4096 + (size_t)(BATCH / RB) * ABLK;

    prep_wq<<<FT, 192, 0, stream>>>(W_ft, Wq, invs);
    if (ws_size >= needed) {
        conv_boards<<<2048, 256, 0, stream>>>(board_stm, board_nstm, a8f);
        nnue_mfma<true><<<BATCH / RB, THREADS, 0, stream>>>(
            board_stm, board_nstm, a8f, Wq, invs, b_ft, W_out, b_out, out);
    } else {
        nnue_mfma<false><<<BATCH / RB, THREADS, 0, stream>>>(
            board_stm, board_nstm, a8f, Wq, invs, b_ft, W_out, b_out, out);
    }
}

// Round 10
// 78.859 us; speedup vs baseline: 1.1388x; 1.0945x over previous
//
#include <hip/hip_runtime.h>
#include <stdint.h>

#define BATCH 16384
#define NF 768
#define FT 1024
#define RBB 64              // batch rows per block
#define GR 128              // GEMM rows per block (stm 0-63, nstm 64-127)
#define NRF 8               // row fragments (GR/16)
#define THREADS 512
#define NWAVE 8
#define NKS 12              // 768 / 64 K-steps
#define CH_COLS 512         // cols per block (col-half)
#define ABLK (NKS * NRF * 64 * 16)   // 98304 B fragment-ordered A tile

typedef int i32x4 __attribute__((ext_vector_type(4)));

// ---- prep: W_ft [FT][NF] f32 -> Wq [FT][NF] i8 (per-row scale 127/absmax) --
__global__ __launch_bounds__(192) void prep_wq(const float* __restrict__ W_ft,
                                               char* __restrict__ Wq,
                                               float* __restrict__ invs) {
    const int o = blockIdx.x;
    const int t = threadIdx.x;
    __shared__ float smax[3];
    __shared__ float sscale;
    const float4 v = *(const float4*)(W_ft + (size_t)o * NF + t * 4);
    float m = fmaxf(fmaxf(fabsf(v.x), fabsf(v.y)), fmaxf(fabsf(v.z), fabsf(v.w)));
    #pragma unroll
    for (int s = 32; s > 0; s >>= 1) m = fmaxf(m, __shfl_down(m, s, 64));
    if ((t & 63) == 0) smax[t >> 6] = m;
    __syncthreads();
    if (t == 0) {
        const float am = fmaxf(fmaxf(smax[0], smax[1]), smax[2]);
        sscale = 127.0f / am;
        invs[o] = am / 127.0f;
    }
    __syncthreads();
    const float s = sscale;
    const float arr[4] = {v.x, v.y, v.z, v.w};
    uint32_t pk = 0;
    #pragma unroll
    for (int j = 0; j < 4; ++j) {
        const int q = (int)rintf(arr[j] * s);
        pk |= ((uint32_t)(unsigned char)(char)q) << (8 * j);
    }
    *(uint32_t*)(Wq + (size_t)o * NF + t * 4) = pk;
}

__device__ __forceinline__ uint32_t pack01(float4 v) {
    return (uint32_t)(v.x != 0.0f) | ((uint32_t)(v.y != 0.0f) << 8)
         | ((uint32_t)(v.z != 0.0f) << 16) | ((uint32_t)(v.w != 0.0f) << 24);
}

// ---- fused dense i8-MFMA FT + SCReLU + partial output dot ------------------
// bid: rg = bid>>1 (64 batch rows), ch = bid&1 (512-col half). 8 waves; wave w
// owns cols [ch*512 + 64w, +64). acc[8][4]; A staged f32->i8 frag-order LDS.
__global__ __launch_bounds__(THREADS, 2) void nnue_mfma(
    const float* __restrict__ bstm, const float* __restrict__ bnstm,
    const char* __restrict__ Wq, const float* __restrict__ invs,
    const float* __restrict__ b_ft, const float* __restrict__ W_out,
    float* __restrict__ pbuf)
{
    __shared__ __align__(16) char Albs[ABLK];   // 96 KB
    __shared__ float red[GR][NWAVE];            // 4 KB

    const int t = threadIdx.x;
    const int w = t >> 6;
    const int l = t & 63;
    const int rg = blockIdx.x >> 1;
    const int ch = blockIdx.x & 1;

    // Phase 1: stage 128 board rows -> i8 {0,1} fragment-order LDS.
    // Thread t owns row t&127; 4 threads/row each do 12 of 48 16B-chunks.
    // 3 batches x 16 float4 loads in flight (256-reg budget allows it).
    {
        const int srow = t & 127;
        const int tq = t >> 7;
        const int r = srow >> 4, cl = srow & 15;
        const float* abase = (srow < RBB)
            ? (bstm + (size_t)(rg * RBB + srow) * NF)
            : (bnstm + (size_t)(rg * RBB + srow - RBB) * NF);
        #pragma unroll
        for (int bt = 0; bt < 3; ++bt) {
            float4 v[16];
            #pragma unroll
            for (int cc = 0; cc < 4; ++cc) {
                const int c16 = tq + 4 * (bt * 4 + cc);
                #pragma unroll
                for (int u = 0; u < 4; ++u)
                    v[cc * 4 + u] = *(const float4*)(abase + c16 * 16 + u * 4);
            }
            __builtin_amdgcn_sched_barrier(0);   // keep all 16 loads in flight
            #pragma unroll
            for (int cc = 0; cc < 4; ++cc) {
                const int c16 = tq + 4 * (bt * 4 + cc);
                const int ks = c16 >> 2, q = c16 & 3;
                uint4 o;
                o.x = pack01(v[cc * 4 + 0]); o.y = pack01(v[cc * 4 + 1]);
                o.z = pack01(v[cc * 4 + 2]); o.w = pack01(v[cc * 4 + 3]);
                const int slot = ((ks * NRF + r) << 6) + (q << 4) + cl;
                *(uint4*)(&Albs[(size_t)slot << 4]) = o;
            }
        }
    }
    __syncthreads();

    // Phase 2: K-loop, even/odd B-register pipeline (depth ~2).
    const int cl = l & 15;
    const int q = l >> 4;
    const char* bp = Wq + (size_t)(ch * CH_COLS + w * 64 + cl) * NF + q * 16;
    const i32x4* af = (const i32x4*)Albs;   // af[(ks*8+r)*64 + l]

    i32x4 be[4], bo[4];
    #pragma unroll
    for (int c = 0; c < 4; ++c)
        be[c] = *(const i32x4*)(bp + (size_t)c * 16 * NF);

    i32x4 acc[NRF][4] = {};
    #pragma unroll
    for (int kk = 0; kk < 6; ++kk) {
        const int ks0 = 2 * kk, ks1 = 2 * kk + 1;
        #pragma unroll
        for (int c = 0; c < 4; ++c)
            bo[c] = *(const i32x4*)(bp + (size_t)c * 16 * NF + ks1 * 64);
        __builtin_amdgcn_s_setprio(1);
        #pragma unroll
        for (int r = 0; r < NRF; ++r) {
            const i32x4 a = af[(ks0 * NRF + r) * 64 + l];
            #pragma unroll
            for (int c = 0; c < 4; ++c)
                acc[r][c] = __builtin_amdgcn_mfma_i32_16x16x64_i8(
                    a, be[c], acc[r][c], 0, 0, 0);
        }
        __builtin_amdgcn_s_setprio(0);
        if (kk < 5) {
            #pragma unroll
            for (int c = 0; c < 4; ++c)
                be[c] = *(const i32x4*)(bp + (size_t)c * 16 * NF + (ks1 + 1) * 64);
        }
        __builtin_amdgcn_s_setprio(1);
        #pragma unroll
        for (int r = 0; r < NRF; ++r) {
            const i32x4 a = af[(ks1 * NRF + r) * 64 + l];
            #pragma unroll
            for (int c = 0; c < 4; ++c)
                acc[r][c] = __builtin_amdgcn_mfma_i32_16x16x64_i8(
                    a, bo[c], acc[r][c], 0, 0, 0);
        }
        __builtin_amdgcn_s_setprio(0);
    }

    // Phase 3: dequant + bias + SCReLU + partial W_out dot.
    // C/D lane mapping: col=l&15, row=(l>>4)*4+j (validated r5-r9).
    float ps[NRF][4] = {};
    #pragma unroll
    for (int c = 0; c < 4; ++c) {
        const int col = ch * CH_COLS + w * 64 + c * 16 + cl;
        const float iv = invs[col];
        const float bf = b_ft[col];
        const float wo0 = W_out[col];
        const float wo1 = W_out[FT + col];
        #pragma unroll
        for (int r = 0; r < NRF; ++r) {
            const float wo = (r < 4) ? wo0 : wo1;  // rows 0-63 stm, 64-127 nstm
            #pragma unroll
            for (int j = 0; j < 4; ++j) {
                float h = fmaf((float)acc[r][c][j], iv, bf);
                h = fminf(fmaxf(h, 0.0f), 1.0f);
                ps[r][j] = fmaf(h * h, wo, ps[r][j]);
            }
        }
    }
    #pragma unroll
    for (int r = 0; r < NRF; ++r)
        #pragma unroll
        for (int j = 0; j < 4; ++j) {
            float v = ps[r][j];
            v += __shfl_xor(v, 1, 64);
            v += __shfl_xor(v, 2, 64);
            v += __shfl_xor(v, 4, 64);
            v += __shfl_xor(v, 8, 64);
            if (cl == 0) red[16 * r + 4 * q + j][w] = v;
        }
    __syncthreads();

    // Phase 4: per batch row, stm(g=t) + nstm(g=64+t) over 8 waves -> pbuf.
    if (t < RBB) {
        float x = 0.0f;
        #pragma unroll
        for (int w2 = 0; w2 < NWAVE; ++w2)
            x += red[t][w2] + red[RBB + t][w2];
        pbuf[(size_t)ch * BATCH + rg * RBB + t] = x;
    }
}

// ---- finalize: sum the two col-half partials + bias -> sigmoid -------------
__global__ __launch_bounds__(256) void finalize(const float* __restrict__ pbuf,
                                                const float* __restrict__ b_out,
                                                float* __restrict__ out) {
    const int i = blockIdx.x * 256 + threadIdx.x;
    const float x = pbuf[i] + pbuf[BATCH + i] + b_out[0];
    out[i] = 1.0f / (1.0f + expf(-x));
}

extern "C" void kernel_launch(void* const* d_in, const int* in_sizes, int n_in,
                              void* d_out, int out_size, void* d_ws, size_t ws_size,
                              hipStream_t stream) {
    const float* board_stm  = (const float*)d_in[0];
    const float* board_nstm = (const float*)d_in[1];
    const float* W_ft       = (const float*)d_in[2];
    const float* b_ft       = (const float*)d_in[3];
    const float* W_out      = (const float*)d_in[4];
    const float* b_out      = (const float*)d_in[5];
    float* out = (float*)d_out;

    char* Wq = (char*)d_ws;                                   // 768 KB
    float* invs = (float*)((char*)d_ws + (size_t)FT * NF);    // 4 KB
    float* pbuf = (float*)((char*)d_ws + (size_t)FT * NF + 4096);  // 128 KB

    prep_wq<<<FT, 192, 0, stream>>>(W_ft, Wq, invs);
    nnue_mfma<<<(BATCH / RBB) * 2, THREADS, 0, stream>>>(
        board_stm, board_nstm, Wq, invs, b_ft, W_out, pbuf);
    finalize<<<BATCH / 256, 256, 0, stream>>>(pbuf, b_out, out);
}